// Round 11
// baseline (337.037 us; speedup 1.0000x reference)
//
#include <hip/hip_runtime.h>

// SelfAM, algebraically collapsed:
//   C[b]   = X Xt   (fp32, atomic split-K accumulate)                 K1
//   G[b]   = Wv C Wk^T + bias-cross-terms(s = X 1)                    K3
//   N[b]   = scale * (Wo sigmoid(G)) Wq  [256 x 256]                  K3
//   out[b] = N X + dvec + x                                           K4
// All GEMMs bf16 MFMA 16x16x32. Residual x exact fp32.
//
// MFMA fragment convention (gfx950 v_mfma_f32_16x16x32_bf16):
//   A-frag[j] = A[row = base + (lane&15)][k = 8*(lane>>4) + j]   (A stored [M][K], k-contig)
//   B-frag[j] = B[k   = 8*(lane>>4) + j][col = base + (lane&15)] (B stored [N][K], k-contig)
//   D-frag[r] = D[row = base + 4*(lane>>4) + r][col = base + (lane&15)]
//
// HARD RULES (rounds 4/6/7/9 post-mortems):
//  1) No 2nd __launch_bounds__ arg — hipcc treats it as blocks/CU and
//     collapses the VGPR budget ((512,6)->40, (512,4)->64, both spilled).
//  2) Never feed MFMA operands straight from global at 512B row stride:
//     64 cache lines per frag-load -> latency-dead kernel (round-7 k3).
//  3) k1 commit must stay AFTER the MFMA block (consumes issue(tt+1) loads).
//  4) k4 residual prefetch-to-reg costs +16 VGPR -> 3->2 blocks/CU, net
//     negative (round 9). Leave residual loads in the epilogue.
//  5) Round-noise is ±3 µs — deltas below that are not signal.
// Round-11: k2 eliminated. k1 accumulates split-K partials via fp32
// atomicAdd into a memset-zeroed C_f32 (8 MiB); k3 phase A reads C as
// fp32 frags (ld_g_f32frag — same bf16 rounding point as before).

typedef unsigned int   u32;
typedef unsigned short u16;
typedef __bf16 bf16_t;
typedef bf16_t bf16x8 __attribute__((ext_vector_type(8)));
typedef u16    u16x8  __attribute__((ext_vector_type(8)));
typedef float  f32x4  __attribute__((ext_vector_type(4)));

#define SWZ(row, byte) ((byte) ^ (((row) & 7) << 4))
// k4 Xt swizzle: conflict-free for the transpose write AND the b128 frag read.
#define SWZ4(n, byte) ((byte) ^ ((((((n) >> 2) & 7) ^ (((n) & 3) << 1)) << 4)))
#define SCALE 1.3810679320049757e-3f  // 1/sqrt(128*4096)
#define ZERO4 (f32x4){0.f, 0.f, 0.f, 0.f}

__device__ __forceinline__ u16 f2bf(float f) {
  u32 u = __builtin_bit_cast(u32, f);
  u32 r = (u + 0x7FFFu + ((u >> 16) & 1u)) >> 16;  // RNE
  return (u16)r;
}
__device__ __forceinline__ float bf2f(u16 h) {
  u32 u = ((u32)h) << 16;
  return __builtin_bit_cast(float, u);
}
__device__ __forceinline__ uint2 pack4bf(float a, float b, float c, float d) {
  uint2 r;
  r.x = (u32)f2bf(a) | ((u32)f2bf(b) << 16);
  r.y = (u32)f2bf(c) | ((u32)f2bf(d) << 16);
  return r;
}
__device__ __forceinline__ f32x4 mfma16(bf16x8 a, bf16x8 b, f32x4 c) {
  return __builtin_amdgcn_mfma_f32_16x16x32_bf16(a, b, c, 0, 0, 0);
}
__device__ __forceinline__ bf16x8 ld_lds_frag(const char* base, int row, int rowbytes, int kbyte) {
  return *reinterpret_cast<const bf16x8*>(base + row * rowbytes + SWZ(row, kbyte));
}
__device__ __forceinline__ bf16x8 ld_lds_frag4(const char* base, int row, int rowbytes, int kbyte) {
  return *reinterpret_cast<const bf16x8*>(base + row * rowbytes + SWZ4(row, kbyte));
}
__device__ __forceinline__ bf16x8 ld_g_bf16frag(const u16* base, int row, int rowlen, int kelem) {
  return *reinterpret_cast<const bf16x8*>(base + (size_t)row * rowlen + kelem);
}
__device__ __forceinline__ bf16x8 ld_g_f32frag(const float* base, int row, int rowlen, int kelem) {
  const float* p = base + (size_t)row * rowlen + kelem;
  float4 v0 = *reinterpret_cast<const float4*>(p);
  float4 v1 = *reinterpret_cast<const float4*>(p + 4);
  u16x8 h;
  h[0] = f2bf(v0.x); h[1] = f2bf(v0.y); h[2] = f2bf(v0.z); h[3] = f2bf(v0.w);
  h[4] = f2bf(v1.x); h[5] = f2bf(v1.y); h[6] = f2bf(v1.z); h[7] = f2bf(v1.w);
  return __builtin_bit_cast(bf16x8, h);
}

// ---------------------------------------------------------------------------
// K1: C split-K accumulate. grid(8 kc, 32 b) x 1024 thr. Double-buffered
// LDS staging; epilogue atomicAdds the partial into fp32 C (zeroed upfront).
// ---------------------------------------------------------------------------
__global__ __launch_bounds__(1024) void k1_xxt(const float* __restrict__ x,
                                               float* __restrict__ Cf,
                                               float* __restrict__ s_p) {
  const int kc = blockIdx.x;  // n-chunk 0..7 (512 cols)
  const int b  = blockIdx.y;
  const float* Xb = x + (size_t)b * 1048576;
  __shared__ char sm[65536];  // 2 x [256 ch][64 n] bf16, rowbytes 128, swizzled
  const int t = threadIdx.x;
  const int lane = t & 63;
  const int w = t >> 6, wi = w >> 2, wj = w & 3;  // 4x4 wave grid over 256x256 C
  const int l15 = lane & 15, l4 = lane >> 4;
  const int sd = t >> 4;           // staging row base 0..63
  const int sn2 = (t & 15) * 8;    // staging byte offset (4 bf16)
  const int nbase = kc * 512;

  f32x4 acc[4][4];
#pragma unroll
  for (int i = 0; i < 4; ++i)
#pragma unroll
    for (int j = 0; j < 4; ++j) acc[i][j] = ZERO4;
  float ssum[4] = {0.f, 0.f, 0.f, 0.f};
  float4 stg[4];

  auto issue = [&](int tt) {
    const int n0 = nbase + tt * 64;
#pragma unroll
    for (int i = 0; i < 4; ++i)
      stg[i] = *reinterpret_cast<const float4*>(Xb + (size_t)(sd + 64 * i) * 4096 + n0 + (t & 15) * 4);
  };
  auto commit = [&](int tt) {
    char* B = sm + (tt & 1) * 32768;
#pragma unroll
    for (int i = 0; i < 4; ++i) {
      const int d = sd + 64 * i;
      ssum[i] += stg[i].x + stg[i].y + stg[i].z + stg[i].w;
      *reinterpret_cast<uint2*>(B + d * 128 + SWZ(d, sn2)) = pack4bf(stg[i].x, stg[i].y, stg[i].z, stg[i].w);
    }
  };

  issue(0); commit(0);
  for (int tt = 0; tt < 8; ++tt) {
    if (tt < 7) issue(tt + 1);
    __syncthreads();  // buf[tt&1] ready; all prior reads of buf[(tt+1)&1] done
    const char* Bc = sm + (tt & 1) * 32768;
#pragma unroll
    for (int ks = 0; ks < 2; ++ks) {
      const int kbyte = ks * 64 + l4 * 16;
      bf16x8 fa[4], fb[4];
#pragma unroll
      for (int i = 0; i < 4; ++i) fa[i] = ld_lds_frag(Bc, (4 * wi + i) * 16 + l15, 128, kbyte);
#pragma unroll
      for (int j = 0; j < 4; ++j) fb[j] = ld_lds_frag(Bc, (4 * wj + j) * 16 + l15, 128, kbyte);
#pragma unroll
      for (int i = 0; i < 4; ++i)
#pragma unroll
        for (int j = 0; j < 4; ++j) acc[i][j] = mfma16(fa[i], fb[j], acc[i][j]);
    }
    if (tt < 7) commit(tt + 1);
  }

  // channel row-sum partials (bias cross terms), non-atomic per (kc,b)
#pragma unroll
  for (int i = 0; i < 4; ++i) {
    float v = ssum[i];
    v += __shfl_xor(v, 1); v += __shfl_xor(v, 2);
    v += __shfl_xor(v, 4); v += __shfl_xor(v, 8);
    if (l15 == 0) s_p[(b * 8 + kc) * 256 + sd + 64 * i] = v;
  }
  // atomically accumulate partial C (symmetric -> store transposed = same C)
  float* Cb = Cf + (size_t)b * 65536;
#pragma unroll
  for (int i = 0; i < 4; ++i)
#pragma unroll
    for (int j = 0; j < 4; ++j) {
      const int r0 = 64 * wi + 16 * i + 4 * l4;
      const int c  = 64 * wj + 16 * j + l15;
      f32x4 v = acc[i][j];
#pragma unroll
      for (int r = 0; r < 4; ++r) atomicAdd(&Cb[c * 256 + r0 + r], v[r]);
    }
}

// ---------------------------------------------------------------------------
// K3: per-batch small chain, sliced 8-way. grid 256 x 512 thr, 1 block/CU
// (144 KiB LDS). XCD-chunked wid remap; phase A reads fp32 C frags.
// ---------------------------------------------------------------------------
__global__ __launch_bounds__(512) void k3_chain(
    const float* __restrict__ Cf, const float* __restrict__ Wv, const float* __restrict__ bv,
    const float* __restrict__ Wk, const float* __restrict__ bk, const float* __restrict__ Wq,
    const float* __restrict__ bq, const float* __restrict__ Wo, const float* __restrict__ bo,
    const float* __restrict__ s_p, u16* __restrict__ Ng, float* __restrict__ dvec) {
  const int wid = (blockIdx.x & 7) * 32 + (blockIdx.x >> 3);  // XCD-chunked (256=8x32)
  const int b = wid >> 3, sl = wid & 7;  // o-rows [32*sl, 32*sl+32)
  __shared__ char smA[65536 + 16384];  // Wk -> sigG^T [0:32K) + M-slice at 64K
  __shared__ char smB[65536];          // U^T -> Wq^T
  __shared__ float s_l[256];
  __shared__ float wsv_s[128], wsk_s[128];
  const int t = threadIdx.x;
  const int lane = t & 63;
  const int w = t >> 6;  // 0..7
  const int l15 = lane & 15, l4 = lane >> 4;
  const float* Cb = Cf + (size_t)b * 65536;

  // s_l[ch] = sum of 8 k1 partial row-sums
  if (t < 256) {
    float a = 0.f;
#pragma unroll
    for (int kc = 0; kc < 8; ++kc) a += s_p[(b * 8 + kc) * 256 + t];
    s_l[t] = a;
  }
  // stage Wk bf16 -> smA [128 d][256 q], rowbytes 512
  for (int it = 0; it < 16; ++it) {
    const int flat = it * 512 + t;
    const int row = flat >> 6, col4 = (flat & 63) * 4;
    float4 v = *reinterpret_cast<const float4*>(Wk + row * 256 + col4);
    *reinterpret_cast<uint2*>(smA + row * 512 + SWZ(row, col4 * 2)) = pack4bf(v.x, v.y, v.z, v.w);
  }
  __syncthreads();

  // bias helpers: wsv = Wv s, wsk = Wk s  (float4-vectorized; overlaps phase A)
  if (t < 256) {
    const float* W = (t < 128) ? Wv : Wk;
    const int r = t & 127;
    float a = 0.f;
#pragma unroll 4
    for (int q = 0; q < 256; q += 4) {
      float4 wv = *reinterpret_cast<const float4*>(W + r * 256 + q);
      a += wv.x * s_l[q] + wv.y * s_l[q + 1] + wv.z * s_l[q + 2] + wv.w * s_l[q + 3];
    }
    if (t < 128) wsv_s[r] = a; else wsk_s[r] = a;
  }

  // phase A: U = C @ Wk^T [256 p][128 d]; write U^T -> smB [128 d][256 p]
  {
    const int wi = w >> 1, wj = w & 1;
    f32x4 acc[4][4];
#pragma unroll
    for (int i = 0; i < 4; ++i)
#pragma unroll
      for (int j = 0; j < 4; ++j) acc[i][j] = ZERO4;
#pragma unroll
    for (int ks = 0; ks < 8; ++ks) {
      const int ke = ks * 32 + l4 * 8;
      bf16x8 fa[4], fb[4];
#pragma unroll
      for (int i = 0; i < 4; ++i) fa[i] = ld_g_f32frag(Cb, 64 * wi + 16 * i + l15, 256, ke);
#pragma unroll
      for (int j = 0; j < 4; ++j) fb[j] = ld_lds_frag(smA, 64 * wj + 16 * j + l15, 512, ke * 2);
#pragma unroll
      for (int i = 0; i < 4; ++i)
#pragma unroll
        for (int j = 0; j < 4; ++j) acc[i][j] = mfma16(fa[i], fb[j], acc[i][j]);
    }
#pragma unroll
    for (int i = 0; i < 4; ++i)
#pragma unroll
      for (int j = 0; j < 4; ++j) {
        const int d  = 64 * wj + 16 * j + l15;
        const int p0 = 64 * wi + 16 * i + 4 * l4;
        f32x4 v = acc[i][j];
        *reinterpret_cast<uint2*>(smB + d * 512 + SWZ(d, p0 * 2)) = pack4bf(v[0], v[1], v[2], v[3]);
      }
  }
  __syncthreads();

  // phase B: G = Wv @ U [128 c][128 d]; +bias; sigmoid -> sigG^T smA[0:32K) [128 d][128 c]
  {
    const int wi = w >> 1, wj = w & 1;
    f32x4 acc[2][4];
#pragma unroll
    for (int i = 0; i < 2; ++i)
#pragma unroll
      for (int j = 0; j < 4; ++j) acc[i][j] = ZERO4;
#pragma unroll
    for (int ks = 0; ks < 8; ++ks) {
      const int ke = ks * 32 + l4 * 8;
      bf16x8 fa[2], fb[4];
#pragma unroll
      for (int i = 0; i < 2; ++i) fa[i] = ld_g_f32frag(Wv, 32 * wi + 16 * i + l15, 256, ke);
#pragma unroll
      for (int j = 0; j < 4; ++j) fb[j] = ld_lds_frag(smB, 64 * wj + 16 * j + l15, 512, ke * 2);
#pragma unroll
      for (int i = 0; i < 2; ++i)
#pragma unroll
        for (int j = 0; j < 4; ++j) acc[i][j] = mfma16(fa[i], fb[j], acc[i][j]);
    }
#pragma unroll
    for (int i = 0; i < 2; ++i)
#pragma unroll
      for (int j = 0; j < 4; ++j) {
        const int c0 = 32 * wi + 16 * i + 4 * l4;
        const int d  = 64 * wj + 16 * j + l15;
        const float bkd = bk[d];
        const float aux = wsk_s[d] + 4096.f * bkd;
        u16 h[4];
#pragma unroll
        for (int r = 0; r < 4; ++r) {
          const int c = c0 + r;
          float g = acc[i][j][r] + wsv_s[c] * bkd + bv[c] * aux;
          float sg;
          if (g >= 0.f) sg = 1.f / (1.f + expf(-g));
          else { float e = expf(g); sg = e / (1.f + e); }
          h[r] = f2bf(sg);
        }
        uint2 pk;
        pk.x = (u32)h[0] | ((u32)h[1] << 16);
        pk.y = (u32)h[2] | ((u32)h[3] << 16);
        *reinterpret_cast<uint2*>(smA + d * 256 + SWZ(d, c0 * 2)) = pk;
      }
  }
  __syncthreads();

  // stage Wq^T -> smB [256 p][128 d] rowbytes 256  (runs alongside phase C)
  for (int it = 0; it < 16; ++it) {
    const int flat = it * 512 + t;
    const int row = flat >> 6, col4 = (flat & 63) * 4;  // Wq[row d][col p]
    float4 v = *reinterpret_cast<const float4*>(Wq + row * 256 + col4);
    float vv[4] = {v.x, v.y, v.z, v.w};
#pragma unroll
    for (int ii = 0; ii < 4; ++ii) {
      const int col = col4 + ii;
      *reinterpret_cast<u16*>(smB + col * 256 + SWZ(col, row * 2)) = f2bf(vv[ii]);
    }
  }

  // phase C: M-slice [32 o][128 d] = Wo[slice] @ sigG; write -> smA+64K
  {
    const int wr = w >> 2, wc = w & 3;  // 2x4 wave grid, wave tile 16x32
    f32x4 acc[2];
    acc[0] = ZERO4; acc[1] = ZERO4;
#pragma unroll
    for (int ks = 0; ks < 4; ++ks) {
      const int ke = ks * 32 + l4 * 8;
      bf16x8 fa = ld_g_f32frag(Wo, sl * 32 + 16 * wr + l15, 128, ke);
      bf16x8 fb[2];
#pragma unroll
      for (int jj = 0; jj < 2; ++jj) fb[jj] = ld_lds_frag(smA, 32 * wc + 16 * jj + l15, 256, ke * 2);
#pragma unroll
      for (int jj = 0; jj < 2; ++jj) acc[jj] = mfma16(fa, fb[jj], acc[jj]);
    }
#pragma unroll
    for (int jj = 0; jj < 2; ++jj) {
      const int o = 16 * wr + 4 * l4;            // slice-local row
      const int d = 32 * wc + 16 * jj + l15;
#pragma unroll
      for (int r = 0; r < 4; ++r)
        *reinterpret_cast<u16*>(smA + 65536 + (o + r) * 256 + SWZ(o + r, d * 2)) = f2bf(acc[jj][r]);
    }
  }
  __syncthreads();

  // dvec slice: dvec[o] = SCALE * (M bq)[o] + bo[o]
  if (t < 32) {
    float sum = 0.f;
#pragma unroll 4
    for (int d2 = 0; d2 < 128; ++d2)
      sum += bf2f(*reinterpret_cast<const u16*>(smA + 65536 + t * 256 + SWZ(t, d2 * 2))) * bq[d2];
    dvec[b * 256 + sl * 32 + t] = SCALE * sum + bo[sl * 32 + t];
  }

  // phase D: N-slice [32 o][256 p] = SCALE * M @ Wq -> global bf16
  {
    const int wr = w >> 2, wc = w & 3;  // wave tile 16x64
    f32x4 acc[4];
#pragma unroll
    for (int jj = 0; jj < 4; ++jj) acc[jj] = ZERO4;
#pragma unroll
    for (int ks = 0; ks < 4; ++ks) {
      const int kb = (ks * 32 + l4 * 8) * 2;
      bf16x8 fa = ld_lds_frag(smA + 65536, 16 * wr + l15, 256, kb);
      bf16x8 fb[4];
#pragma unroll
      for (int jj = 0; jj < 4; ++jj) fb[jj] = ld_lds_frag(smB, 64 * wc + 16 * jj + l15, 256, kb);
#pragma unroll
      for (int jj = 0; jj < 4; ++jj) acc[jj] = mfma16(fa, fb[jj], acc[jj]);
    }
    u16* Nb = Ng + (size_t)b * 65536;
#pragma unroll
    for (int jj = 0; jj < 4; ++jj) {
      const int o0 = sl * 32 + 16 * wr + 4 * l4;
      const int p  = 64 * wc + 16 * jj + l15;
#pragma unroll
      for (int r = 0; r < 4; ++r)
        Nb[(size_t)(o0 + r) * 256 + p] = f2bf(SCALE * acc[jj][r]);
    }
  }
}

// ---------------------------------------------------------------------------
// K4: out = N X + dvec + x. grid 1024 x 512 thr. XCD-chunked wid remap
// (1024 = 8 XCD x 128): batch b's 32 blocks land on one XCD -> x[b]/N[b]
// L2-local. N in registers; dbuf X^T tile, SWZ4; vectorized transpose-commit.
// ---------------------------------------------------------------------------
__global__ __launch_bounds__(512) void k4_out(const float* __restrict__ x,
                                              const u16* __restrict__ Ng,
                                              const float* __restrict__ dvec,
                                              float* __restrict__ out) {
  const int wid = (blockIdx.x & 7) * 128 + (blockIdx.x >> 3);  // XCD-chunked
  const int b = wid >> 5, nc = wid & 31;  // 128 n-cols per block
  __shared__ char Xt[32768];  // 2 x [32 n][256 p] bf16 rowbytes 512, SWZ4
  const int t = threadIdx.x, lane = t & 63, w = t >> 6;
  const int l15 = lane & 15, l4 = lane >> 4;
  const float* xb = x + (size_t)b * 1048576;
  float* ob = out + (size_t)b * 1048576;
  const u16* Nb = Ng + (size_t)b * 65536;

  // per-wave N slice [32 o][256 p] in registers (16 frags = 64 VGPR)
  bf16x8 bn[2][8];
  float dv[2];
#pragma unroll
  for (int j = 0; j < 2; ++j) {
    const int o = 32 * w + 16 * j + l15;
    dv[j] = dvec[b * 256 + o];
#pragma unroll
    for (int ks = 0; ks < 8; ++ks) bn[j][ks] = ld_g_bf16frag(Nb, o, 256, ks * 32 + l4 * 8);
  }

  const int p0 = (t >> 3) * 4;      // 4 consecutive p-rows per thread
  const int nn = (t & 7) * 4;       // 4 consecutive n per thread
  float4 stg[4];
  auto issue = [&](int sub) {
    const int n0 = nc * 128 + sub * 32;
#pragma unroll
    for (int q = 0; q < 4; ++q)
      stg[q] = *reinterpret_cast<const float4*>(xb + (size_t)(p0 + q) * 4096 + n0 + nn);
  };
  auto commit = [&](int sub) {
    char* B = Xt + (sub & 1) * 16384;
    // in-register 4x4 transpose: row n gets x[p0..p0+3][n]
    *reinterpret_cast<uint2*>(B + (nn + 0) * 512 + SWZ4(nn + 0, p0 * 2)) = pack4bf(stg[0].x, stg[1].x, stg[2].x, stg[3].x);
    *reinterpret_cast<uint2*>(B + (nn + 1) * 512 + SWZ4(nn + 1, p0 * 2)) = pack4bf(stg[0].y, stg[1].y, stg[2].y, stg[3].y);
    *reinterpret_cast<uint2*>(B + (nn + 2) * 512 + SWZ4(nn + 2, p0 * 2)) = pack4bf(stg[0].z, stg[1].z, stg[2].z, stg[3].z);
    *reinterpret_cast<uint2*>(B + (nn + 3) * 512 + SWZ4(nn + 3, p0 * 2)) = pack4bf(stg[0].w, stg[1].w, stg[2].w, stg[3].w);
  };

  issue(0); commit(0);
  for (int sub = 0; sub < 4; ++sub) {
    if (sub < 3) issue(sub + 1);
    __syncthreads();  // buf[sub&1] ready; prior reads of buf[(sub+1)&1] done
    const char* Bc = Xt + (sub & 1) * 16384;
    const int n0 = nc * 128 + sub * 32;
    f32x4 acc[2][2];
#pragma unroll
    for (int i = 0; i < 2; ++i)
#pragma unroll
      for (int j = 0; j < 2; ++j) acc[i][j] = ZERO4;
#pragma unroll
    for (int ks = 0; ks < 8; ++ks) {
      bf16x8 fa[2];
#pragma unroll
      for (int i = 0; i < 2; ++i) fa[i] = ld_lds_frag4(Bc, 16 * i + l15, 512, (ks * 32 + l4 * 8) * 2);
#pragma unroll
      for (int i = 0; i < 2; ++i)
#pragma unroll
        for (int j = 0; j < 2; ++j) acc[i][j] = mfma16(fa[i], bn[j][ks], acc[i][j]);
    }
    // epilogue: out[o][n] = acc^T + dvec[o] + x[o][n]  (residual read L2-hot)
#pragma unroll
    for (int i = 0; i < 2; ++i)
#pragma unroll
      for (int j = 0; j < 2; ++j) {
        const int gn = n0 + 16 * i + 4 * l4;
        const int o  = 32 * w + 16 * j + l15;
        float4 res = *reinterpret_cast<const float4*>(xb + (size_t)o * 4096 + gn);
        float4 ov;
        ov.x = acc[i][j][0] + dv[j] + res.x;
        ov.y = acc[i][j][1] + dv[j] + res.y;
        ov.z = acc[i][j][2] + dv[j] + res.z;
        ov.w = acc[i][j][3] + dv[j] + res.w;
        *reinterpret_cast<float4*>(ob + (size_t)o * 4096 + gn) = ov;
      }
    if (sub < 3) commit(sub + 1);
  }
}

// ---------------------------------------------------------------------------
extern "C" void kernel_launch(void* const* d_in, const int* in_sizes, int n_in,
                              void* d_out, int out_size, void* d_ws, size_t ws_size,
                              hipStream_t stream) {
  (void)in_sizes; (void)n_in; (void)out_size; (void)ws_size;
  const float* x  = (const float*)d_in[0];
  const float* Wv = (const float*)d_in[1];
  const float* bv = (const float*)d_in[2];
  const float* Wk = (const float*)d_in[3];
  const float* bk = (const float*)d_in[4];
  const float* Wq = (const float*)d_in[5];
  const float* bq = (const float*)d_in[6];
  const float* Wo = (const float*)d_in[7];
  const float* bo = (const float*)d_in[8];
  float* out = (float*)d_out;

  char* ws = (char*)d_ws;
  float* Cf  = (float*)(ws);                  // [32][256][256] fp32:    8 MiB
  float* s_p = (float*)(ws + 8388608);        // [32][8][256] fp32:     32 KiB
  u16*   Ng  = (u16*)(ws + 8421376);          // [32][256][256] bf16:    4 MiB
  float* dv  = (float*)(ws + 12615680);       // [32][256] fp32:        32 KiB

  hipMemsetAsync(Cf, 0, 8388608, stream);
  hipLaunchKernelGGL(k1_xxt,  dim3(8, 32), dim3(1024), 0, stream, x, Cf, s_p);
  hipLaunchKernelGGL(k3_chain, dim3(256),  dim3(512),  0, stream,
                     Cf, Wv, bv, Wk, bk, Wq, bq, Wo, bo, s_p, Ng, dv);
  hipLaunchKernelGGL(k4_out,  dim3(1024),  dim3(512),  0, stream, x, Ng, dv, out);
}

// Round 12
// 147.264 us; speedup vs baseline: 2.2887x; 2.2887x over previous
//
#include <hip/hip_runtime.h>

// SelfAM, algebraically collapsed:
//   C[b]   = X Xt              (X = x[b] viewed [256, 4096])          K1 + K2
//   G[b]   = Wv C Wk^T + bias-cross-terms(s = X 1)                    K3
//   N[b]   = scale * (Wo sigmoid(G)) Wq  [256 x 256]                  K3
//   out[b] = N X + dvec + x                                           K4
// All GEMMs bf16 MFMA 16x16x32. Residual x exact fp32.
//
// MFMA fragment convention (gfx950 v_mfma_f32_16x16x32_bf16):
//   A-frag[j] = A[row = base + (lane&15)][k = 8*(lane>>4) + j]   (A stored [M][K], k-contig)
//   B-frag[j] = B[k   = 8*(lane>>4) + j][col = base + (lane&15)] (B stored [N][K], k-contig)
//   D-frag[r] = D[row = base + 4*(lane>>4) + r][col = base + (lane&15)]
//
// HARD RULES (rounds 4/6/7/9/11 post-mortems):
//  1) No 2nd __launch_bounds__ arg — hipcc treats it as blocks/CU and
//     collapses the VGPR budget ((512,6)->40, (512,4)->64, both spilled).
//  2) Never feed MFMA operands straight from global at 512B row stride:
//     64 cache lines per frag-load -> latency-dead kernel (round-7 k3).
//  3) k1 commit must stay AFTER the MFMA block (consumes issue(tt+1) loads).
//  4) k4 residual prefetch-to-reg costs +16 VGPR -> 3->2 blocks/CU, net
//     negative (round 9). Leave residual loads in the epilogue.
//  5) Round-noise is ±3 µs — deltas below that are not signal.
//  6) Never bulk-accumulate split-K via scalar device atomics: 16.7M fp32
//     atomicAdds ran at the cross-XCD coherence point = 246us, WRITE 266MB
//     (round 11). Partials + data-parallel reduce pass is 10x faster.
// This round: exact revert to round-10 (148.2us best): P partials + k2_sum,
// XCD-chunked k3/k4, SWZ4 k4 tile, vectorized transpose-commit.

typedef unsigned int   u32;
typedef unsigned short u16;
typedef __bf16 bf16_t;
typedef bf16_t bf16x8 __attribute__((ext_vector_type(8)));
typedef u16    u16x8  __attribute__((ext_vector_type(8)));
typedef float  f32x4  __attribute__((ext_vector_type(4)));

#define SWZ(row, byte) ((byte) ^ (((row) & 7) << 4))
// k4 Xt swizzle: conflict-free for the transpose write AND the b128 frag read.
#define SWZ4(n, byte) ((byte) ^ ((((((n) >> 2) & 7) ^ (((n) & 3) << 1)) << 4)))
#define SCALE 1.3810679320049757e-3f  // 1/sqrt(128*4096)
#define ZERO4 (f32x4){0.f, 0.f, 0.f, 0.f}

__device__ __forceinline__ u16 f2bf(float f) {
  u32 u = __builtin_bit_cast(u32, f);
  u32 r = (u + 0x7FFFu + ((u >> 16) & 1u)) >> 16;  // RNE
  return (u16)r;
}
__device__ __forceinline__ float bf2f(u16 h) {
  u32 u = ((u32)h) << 16;
  return __builtin_bit_cast(float, u);
}
__device__ __forceinline__ uint2 pack4bf(float a, float b, float c, float d) {
  uint2 r;
  r.x = (u32)f2bf(a) | ((u32)f2bf(b) << 16);
  r.y = (u32)f2bf(c) | ((u32)f2bf(d) << 16);
  return r;
}
__device__ __forceinline__ f32x4 mfma16(bf16x8 a, bf16x8 b, f32x4 c) {
  return __builtin_amdgcn_mfma_f32_16x16x32_bf16(a, b, c, 0, 0, 0);
}
__device__ __forceinline__ bf16x8 ld_lds_frag(const char* base, int row, int rowbytes, int kbyte) {
  return *reinterpret_cast<const bf16x8*>(base + row * rowbytes + SWZ(row, kbyte));
}
__device__ __forceinline__ bf16x8 ld_lds_frag4(const char* base, int row, int rowbytes, int kbyte) {
  return *reinterpret_cast<const bf16x8*>(base + row * rowbytes + SWZ4(row, kbyte));
}
__device__ __forceinline__ bf16x8 ld_g_bf16frag(const u16* base, int row, int rowlen, int kelem) {
  return *reinterpret_cast<const bf16x8*>(base + (size_t)row * rowlen + kelem);
}
__device__ __forceinline__ bf16x8 ld_g_f32frag(const float* base, int row, int rowlen, int kelem) {
  const float* p = base + (size_t)row * rowlen + kelem;
  float4 v0 = *reinterpret_cast<const float4*>(p);
  float4 v1 = *reinterpret_cast<const float4*>(p + 4);
  u16x8 h;
  h[0] = f2bf(v0.x); h[1] = f2bf(v0.y); h[2] = f2bf(v0.z); h[3] = f2bf(v0.w);
  h[4] = f2bf(v1.x); h[5] = f2bf(v1.y); h[6] = f2bf(v1.z); h[7] = f2bf(v1.w);
  return __builtin_bit_cast(bf16x8, h);
}

// ---------------------------------------------------------------------------
// K1: C-partials. grid(8 kc, 32 b) x 1024 thr. Double-buffered LDS staging.
// ---------------------------------------------------------------------------
__global__ __launch_bounds__(1024) void k1_xxt(const float* __restrict__ x,
                                               u16* __restrict__ P,
                                               float* __restrict__ s_p) {
  const int kc = blockIdx.x;  // n-chunk 0..7 (512 cols)
  const int b  = blockIdx.y;
  const float* Xb = x + (size_t)b * 1048576;
  __shared__ char sm[65536];  // 2 x [256 ch][64 n] bf16, rowbytes 128, swizzled
  const int t = threadIdx.x;
  const int lane = t & 63;
  const int w = t >> 6, wi = w >> 2, wj = w & 3;  // 4x4 wave grid over 256x256 C
  const int l15 = lane & 15, l4 = lane >> 4;
  const int sd = t >> 4;           // staging row base 0..63
  const int sn2 = (t & 15) * 8;    // staging byte offset (4 bf16)
  const int nbase = kc * 512;

  f32x4 acc[4][4];
#pragma unroll
  for (int i = 0; i < 4; ++i)
#pragma unroll
    for (int j = 0; j < 4; ++j) acc[i][j] = ZERO4;
  float ssum[4] = {0.f, 0.f, 0.f, 0.f};
  float4 stg[4];

  auto issue = [&](int tt) {
    const int n0 = nbase + tt * 64;
#pragma unroll
    for (int i = 0; i < 4; ++i)
      stg[i] = *reinterpret_cast<const float4*>(Xb + (size_t)(sd + 64 * i) * 4096 + n0 + (t & 15) * 4);
  };
  auto commit = [&](int tt) {
    char* B = sm + (tt & 1) * 32768;
#pragma unroll
    for (int i = 0; i < 4; ++i) {
      const int d = sd + 64 * i;
      ssum[i] += stg[i].x + stg[i].y + stg[i].z + stg[i].w;
      *reinterpret_cast<uint2*>(B + d * 128 + SWZ(d, sn2)) = pack4bf(stg[i].x, stg[i].y, stg[i].z, stg[i].w);
    }
  };

  issue(0); commit(0);
  for (int tt = 0; tt < 8; ++tt) {
    if (tt < 7) issue(tt + 1);
    __syncthreads();  // buf[tt&1] ready; all prior reads of buf[(tt+1)&1] done
    const char* Bc = sm + (tt & 1) * 32768;
#pragma unroll
    for (int ks = 0; ks < 2; ++ks) {
      const int kbyte = ks * 64 + l4 * 16;
      bf16x8 fa[4], fb[4];
#pragma unroll
      for (int i = 0; i < 4; ++i) fa[i] = ld_lds_frag(Bc, (4 * wi + i) * 16 + l15, 128, kbyte);
#pragma unroll
      for (int j = 0; j < 4; ++j) fb[j] = ld_lds_frag(Bc, (4 * wj + j) * 16 + l15, 128, kbyte);
#pragma unroll
      for (int i = 0; i < 4; ++i)
#pragma unroll
        for (int j = 0; j < 4; ++j) acc[i][j] = mfma16(fa[i], fb[j], acc[i][j]);
    }
    if (tt < 7) commit(tt + 1);
  }

  // channel row-sum partials (bias cross terms), non-atomic per (kc,b)
#pragma unroll
  for (int i = 0; i < 4; ++i) {
    float v = ssum[i];
    v += __shfl_xor(v, 1); v += __shfl_xor(v, 2);
    v += __shfl_xor(v, 4); v += __shfl_xor(v, 8);
    if (l15 == 0) s_p[(b * 8 + kc) * 256 + sd + 64 * i] = v;
  }
  // write partial C (symmetric -> store transposed = same matrix), packed 8B
  u16* Pb = P + ((size_t)(b * 8 + kc)) * 65536;
#pragma unroll
  for (int i = 0; i < 4; ++i)
#pragma unroll
    for (int j = 0; j < 4; ++j) {
      const int r0 = 64 * wi + 16 * i + 4 * l4;
      const int c  = 64 * wj + 16 * j + l15;
      f32x4 v = acc[i][j];
      *reinterpret_cast<uint2*>(Pb + (size_t)c * 256 + r0) = pack4bf(v[0], v[1], v[2], v[3]);
    }
}

// ---------------------------------------------------------------------------
// K2: sum 8 partials -> C bf16.  grid 1024 x 256, 8 elems/thread
// ---------------------------------------------------------------------------
__global__ __launch_bounds__(256) void k2_sum(const u16* __restrict__ P, u16* __restrict__ C) {
  const size_t idx = ((size_t)blockIdx.x * 256 + threadIdx.x) * 8;
  const size_t b = idx >> 16, e = idx & 65535;
  const u16* base = P + b * 8 * 65536 + e;
  float acc[8];
#pragma unroll
  for (int q = 0; q < 8; ++q) acc[q] = 0.f;
#pragma unroll
  for (int kc = 0; kc < 8; ++kc) {
    uint4 v = *reinterpret_cast<const uint4*>(base + (size_t)kc * 65536);
    u32 a4[4] = {v.x, v.y, v.z, v.w};
#pragma unroll
    for (int q = 0; q < 4; ++q) {
      acc[2 * q]     += bf2f((u16)(a4[q] & 0xFFFFu));
      acc[2 * q + 1] += bf2f((u16)(a4[q] >> 16));
    }
  }
  uint4 o;
  o.x = (u32)f2bf(acc[0]) | ((u32)f2bf(acc[1]) << 16);
  o.y = (u32)f2bf(acc[2]) | ((u32)f2bf(acc[3]) << 16);
  o.z = (u32)f2bf(acc[4]) | ((u32)f2bf(acc[5]) << 16);
  o.w = (u32)f2bf(acc[6]) | ((u32)f2bf(acc[7]) << 16);
  *reinterpret_cast<uint4*>(C + b * 65536 + e) = o;
}

// ---------------------------------------------------------------------------
// K3: per-batch small chain, sliced 8-way (round-5 structure, proven good).
// grid 256 x 512 thr, 1 block/CU (144 KiB LDS). XCD-chunked wid remap:
// a batch's 8 slice-blocks share C[b]+weights on one XCD's L2.
// ---------------------------------------------------------------------------
__global__ __launch_bounds__(512) void k3_chain(
    const u16* __restrict__ C, const float* __restrict__ Wv, const float* __restrict__ bv,
    const float* __restrict__ Wk, const float* __restrict__ bk, const float* __restrict__ Wq,
    const float* __restrict__ bq, const float* __restrict__ Wo, const float* __restrict__ bo,
    const float* __restrict__ s_p, u16* __restrict__ Ng, float* __restrict__ dvec) {
  const int wid = (blockIdx.x & 7) * 32 + (blockIdx.x >> 3);  // XCD-chunked (256=8x32)
  const int b = wid >> 3, sl = wid & 7;  // o-rows [32*sl, 32*sl+32)
  __shared__ char smA[65536 + 16384];  // Wk -> sigG^T [0:32K) + M-slice at 64K
  __shared__ char smB[65536];          // U^T -> Wq^T
  __shared__ float s_l[256];
  __shared__ float wsv_s[128], wsk_s[128];
  const int t = threadIdx.x;
  const int lane = t & 63;
  const int w = t >> 6;  // 0..7
  const int l15 = lane & 15, l4 = lane >> 4;
  const u16* Cb = C + (size_t)b * 65536;

  // s_l[ch] = sum of 8 k1 partial row-sums
  if (t < 256) {
    float a = 0.f;
#pragma unroll
    for (int kc = 0; kc < 8; ++kc) a += s_p[(b * 8 + kc) * 256 + t];
    s_l[t] = a;
  }
  // stage Wk bf16 -> smA [128 d][256 q], rowbytes 512
  for (int it = 0; it < 16; ++it) {
    const int flat = it * 512 + t;
    const int row = flat >> 6, col4 = (flat & 63) * 4;
    float4 v = *reinterpret_cast<const float4*>(Wk + row * 256 + col4);
    *reinterpret_cast<uint2*>(smA + row * 512 + SWZ(row, col4 * 2)) = pack4bf(v.x, v.y, v.z, v.w);
  }
  __syncthreads();

  // bias helpers: wsv = Wv s, wsk = Wk s  (float4-vectorized; overlaps phase A)
  if (t < 256) {
    const float* W = (t < 128) ? Wv : Wk;
    const int r = t & 127;
    float a = 0.f;
#pragma unroll 4
    for (int q = 0; q < 256; q += 4) {
      float4 wv = *reinterpret_cast<const float4*>(W + r * 256 + q);
      a += wv.x * s_l[q] + wv.y * s_l[q + 1] + wv.z * s_l[q + 2] + wv.w * s_l[q + 3];
    }
    if (t < 128) wsv_s[r] = a; else wsk_s[r] = a;
  }

  // phase A: U = C @ Wk^T [256 p][128 d]; write U^T -> smB [128 d][256 p]
  {
    const int wi = w >> 1, wj = w & 1;
    f32x4 acc[4][4];
#pragma unroll
    for (int i = 0; i < 4; ++i)
#pragma unroll
      for (int j = 0; j < 4; ++j) acc[i][j] = ZERO4;
#pragma unroll
    for (int ks = 0; ks < 8; ++ks) {
      const int ke = ks * 32 + l4 * 8;
      bf16x8 fa[4], fb[4];
#pragma unroll
      for (int i = 0; i < 4; ++i) fa[i] = ld_g_bf16frag(Cb, 64 * wi + 16 * i + l15, 256, ke);
#pragma unroll
      for (int j = 0; j < 4; ++j) fb[j] = ld_lds_frag(smA, 64 * wj + 16 * j + l15, 512, ke * 2);
#pragma unroll
      for (int i = 0; i < 4; ++i)
#pragma unroll
        for (int j = 0; j < 4; ++j) acc[i][j] = mfma16(fa[i], fb[j], acc[i][j]);
    }
#pragma unroll
    for (int i = 0; i < 4; ++i)
#pragma unroll
      for (int j = 0; j < 4; ++j) {
        const int d  = 64 * wj + 16 * j + l15;
        const int p0 = 64 * wi + 16 * i + 4 * l4;
        f32x4 v = acc[i][j];
        *reinterpret_cast<uint2*>(smB + d * 512 + SWZ(d, p0 * 2)) = pack4bf(v[0], v[1], v[2], v[3]);
      }
  }
  __syncthreads();

  // phase B: G = Wv @ U [128 c][128 d]; +bias; sigmoid -> sigG^T smA[0:32K) [128 d][128 c]
  {
    const int wi = w >> 1, wj = w & 1;
    f32x4 acc[2][4];
#pragma unroll
    for (int i = 0; i < 2; ++i)
#pragma unroll
      for (int j = 0; j < 4; ++j) acc[i][j] = ZERO4;
#pragma unroll
    for (int ks = 0; ks < 8; ++ks) {
      const int ke = ks * 32 + l4 * 8;
      bf16x8 fa[2], fb[4];
#pragma unroll
      for (int i = 0; i < 2; ++i) fa[i] = ld_g_f32frag(Wv, 32 * wi + 16 * i + l15, 256, ke);
#pragma unroll
      for (int j = 0; j < 4; ++j) fb[j] = ld_lds_frag(smB, 64 * wj + 16 * j + l15, 512, ke * 2);
#pragma unroll
      for (int i = 0; i < 2; ++i)
#pragma unroll
        for (int j = 0; j < 4; ++j) acc[i][j] = mfma16(fa[i], fb[j], acc[i][j]);
    }
#pragma unroll
    for (int i = 0; i < 2; ++i)
#pragma unroll
      for (int j = 0; j < 4; ++j) {
        const int c0 = 32 * wi + 16 * i + 4 * l4;
        const int d  = 64 * wj + 16 * j + l15;
        const float bkd = bk[d];
        const float aux = wsk_s[d] + 4096.f * bkd;
        u16 h[4];
#pragma unroll
        for (int r = 0; r < 4; ++r) {
          const int c = c0 + r;
          float g = acc[i][j][r] + wsv_s[c] * bkd + bv[c] * aux;
          float sg;
          if (g >= 0.f) sg = 1.f / (1.f + expf(-g));
          else { float e = expf(g); sg = e / (1.f + e); }
          h[r] = f2bf(sg);
        }
        uint2 pk;
        pk.x = (u32)h[0] | ((u32)h[1] << 16);
        pk.y = (u32)h[2] | ((u32)h[3] << 16);
        *reinterpret_cast<uint2*>(smA + d * 256 + SWZ(d, c0 * 2)) = pk;
      }
  }
  __syncthreads();

  // stage Wq^T -> smB [256 p][128 d] rowbytes 256  (runs alongside phase C)
  for (int it = 0; it < 16; ++it) {
    const int flat = it * 512 + t;
    const int row = flat >> 6, col4 = (flat & 63) * 4;  // Wq[row d][col p]
    float4 v = *reinterpret_cast<const float4*>(Wq + row * 256 + col4);
    float vv[4] = {v.x, v.y, v.z, v.w};
#pragma unroll
    for (int ii = 0; ii < 4; ++ii) {
      const int col = col4 + ii;
      *reinterpret_cast<u16*>(smB + col * 256 + SWZ(col, row * 2)) = f2bf(vv[ii]);
    }
  }

  // phase C: M-slice [32 o][128 d] = Wo[slice] @ sigG; write -> smA+64K
  {
    const int wr = w >> 2, wc = w & 3;  // 2x4 wave grid, wave tile 16x32
    f32x4 acc[2];
    acc[0] = ZERO4; acc[1] = ZERO4;
#pragma unroll
    for (int ks = 0; ks < 4; ++ks) {
      const int ke = ks * 32 + l4 * 8;
      bf16x8 fa = ld_g_f32frag(Wo, sl * 32 + 16 * wr + l15, 128, ke);
      bf16x8 fb[2];
#pragma unroll
      for (int jj = 0; jj < 2; ++jj) fb[jj] = ld_lds_frag(smA, 32 * wc + 16 * jj + l15, 256, ke * 2);
#pragma unroll
      for (int jj = 0; jj < 2; ++jj) acc[jj] = mfma16(fa, fb[jj], acc[jj]);
    }
#pragma unroll
    for (int jj = 0; jj < 2; ++jj) {
      const int o = 16 * wr + 4 * l4;            // slice-local row
      const int d = 32 * wc + 16 * jj + l15;
#pragma unroll
      for (int r = 0; r < 4; ++r)
        *reinterpret_cast<u16*>(smA + 65536 + (o + r) * 256 + SWZ(o + r, d * 2)) = f2bf(acc[jj][r]);
    }
  }
  __syncthreads();

  // dvec slice: dvec[o] = SCALE * (M bq)[o] + bo[o]
  if (t < 32) {
    float sum = 0.f;
#pragma unroll 4
    for (int d2 = 0; d2 < 128; ++d2)
      sum += bf2f(*reinterpret_cast<const u16*>(smA + 65536 + t * 256 + SWZ(t, d2 * 2))) * bq[d2];
    dvec[b * 256 + sl * 32 + t] = SCALE * sum + bo[sl * 32 + t];
  }

  // phase D: N-slice [32 o][256 p] = SCALE * M @ Wq -> global bf16
  {
    const int wr = w >> 2, wc = w & 3;  // wave tile 16x64
    f32x4 acc[4];
#pragma unroll
    for (int jj = 0; jj < 4; ++jj) acc[jj] = ZERO4;
#pragma unroll
    for (int ks = 0; ks < 4; ++ks) {
      const int kb = (ks * 32 + l4 * 8) * 2;
      bf16x8 fa = ld_lds_frag(smA + 65536, 16 * wr + l15, 256, kb);
      bf16x8 fb[4];
#pragma unroll
      for (int jj = 0; jj < 4; ++jj) fb[jj] = ld_lds_frag(smB, 64 * wc + 16 * jj + l15, 256, kb);
#pragma unroll
      for (int jj = 0; jj < 4; ++jj) acc[jj] = mfma16(fa, fb[jj], acc[jj]);
    }
    u16* Nb = Ng + (size_t)b * 65536;
#pragma unroll
    for (int jj = 0; jj < 4; ++jj) {
      const int o0 = sl * 32 + 16 * wr + 4 * l4;
      const int p  = 64 * wc + 16 * jj + l15;
#pragma unroll
      for (int r = 0; r < 4; ++r)
        Nb[(size_t)(o0 + r) * 256 + p] = f2bf(SCALE * acc[jj][r]);
    }
  }
}

// ---------------------------------------------------------------------------
// K4: out = N X + dvec + x. grid 1024 x 512 thr. XCD-chunked wid remap
// (1024 = 8 XCD x 128): batch b's 32 blocks land on one XCD -> x[b]/N[b]
// L2-local. N in registers; dbuf X^T tile, SWZ4; vectorized transpose-commit.
// ---------------------------------------------------------------------------
__global__ __launch_bounds__(512) void k4_out(const float* __restrict__ x,
                                              const u16* __restrict__ Ng,
                                              const float* __restrict__ dvec,
                                              float* __restrict__ out) {
  const int wid = (blockIdx.x & 7) * 128 + (blockIdx.x >> 3);  // XCD-chunked
  const int b = wid >> 5, nc = wid & 31;  // 128 n-cols per block
  __shared__ char Xt[32768];  // 2 x [32 n][256 p] bf16 rowbytes 512, SWZ4
  const int t = threadIdx.x, lane = t & 63, w = t >> 6;
  const int l15 = lane & 15, l4 = lane >> 4;
  const float* xb = x + (size_t)b * 1048576;
  float* ob = out + (size_t)b * 1048576;
  const u16* Nb = Ng + (size_t)b * 65536;

  // per-wave N slice [32 o][256 p] in registers (16 frags = 64 VGPR)
  bf16x8 bn[2][8];
  float dv[2];
#pragma unroll
  for (int j = 0; j < 2; ++j) {
    const int o = 32 * w + 16 * j + l15;
    dv[j] = dvec[b * 256 + o];
#pragma unroll
    for (int ks = 0; ks < 8; ++ks) bn[j][ks] = ld_g_bf16frag(Nb, o, 256, ks * 32 + l4 * 8);
  }

  const int p0 = (t >> 3) * 4;      // 4 consecutive p-rows per thread
  const int nn = (t & 7) * 4;       // 4 consecutive n per thread
  float4 stg[4];
  auto issue = [&](int sub) {
    const int n0 = nc * 128 + sub * 32;
#pragma unroll
    for (int q = 0; q < 4; ++q)
      stg[q] = *reinterpret_cast<const float4*>(xb + (size_t)(p0 + q) * 4096 + n0 + nn);
  };
  auto commit = [&](int sub) {
    char* B = Xt + (sub & 1) * 16384;
    // in-register 4x4 transpose: row n gets x[p0..p0+3][n]
    *reinterpret_cast<uint2*>(B + (nn + 0) * 512 + SWZ4(nn + 0, p0 * 2)) = pack4bf(stg[0].x, stg[1].x, stg[2].x, stg[3].x);
    *reinterpret_cast<uint2*>(B + (nn + 1) * 512 + SWZ4(nn + 1, p0 * 2)) = pack4bf(stg[0].y, stg[1].y, stg[2].y, stg[3].y);
    *reinterpret_cast<uint2*>(B + (nn + 2) * 512 + SWZ4(nn + 2, p0 * 2)) = pack4bf(stg[0].z, stg[1].z, stg[2].z, stg[3].z);
    *reinterpret_cast<uint2*>(B + (nn + 3) * 512 + SWZ4(nn + 3, p0 * 2)) = pack4bf(stg[0].w, stg[1].w, stg[2].w, stg[3].w);
  };

  issue(0); commit(0);
  for (int sub = 0; sub < 4; ++sub) {
    if (sub < 3) issue(sub + 1);
    __syncthreads();  // buf[sub&1] ready; prior reads of buf[(sub+1)&1] done
    const char* Bc = Xt + (sub & 1) * 16384;
    const int n0 = nc * 128 + sub * 32;
    f32x4 acc[2][2];
#pragma unroll
    for (int i = 0; i < 2; ++i)
#pragma unroll
      for (int j = 0; j < 2; ++j) acc[i][j] = ZERO4;
#pragma unroll
    for (int ks = 0; ks < 8; ++ks) {
      bf16x8 fa[2];
#pragma unroll
      for (int i = 0; i < 2; ++i) fa[i] = ld_lds_frag4(Bc, 16 * i + l15, 512, (ks * 32 + l4 * 8) * 2);
#pragma unroll
      for (int i = 0; i < 2; ++i)
#pragma unroll
        for (int j = 0; j < 2; ++j) acc[i][j] = mfma16(fa[i], bn[j][ks], acc[i][j]);
    }
    // epilogue: out[o][n] = acc^T + dvec[o] + x[o][n]  (residual read L2-hot)
#pragma unroll
    for (int i = 0; i < 2; ++i)
#pragma unroll
      for (int j = 0; j < 2; ++j) {
        const int gn = n0 + 16 * i + 4 * l4;
        const int o  = 32 * w + 16 * j + l15;
        float4 res = *reinterpret_cast<const float4*>(xb + (size_t)o * 4096 + gn);
        float4 ov;
        ov.x = acc[i][j][0] + dv[j] + res.x;
        ov.y = acc[i][j][1] + dv[j] + res.y;
        ov.z = acc[i][j][2] + dv[j] + res.z;
        ov.w = acc[i][j][3] + dv[j] + res.w;
        *reinterpret_cast<float4*>(ob + (size_t)o * 4096 + gn) = ov;
      }
    if (sub < 3) commit(sub + 1);
  }
}

// ---------------------------------------------------------------------------
extern "C" void kernel_launch(void* const* d_in, const int* in_sizes, int n_in,
                              void* d_out, int out_size, void* d_ws, size_t ws_size,
                              hipStream_t stream) {
  (void)in_sizes; (void)n_in; (void)out_size; (void)ws_size;
  const float* x  = (const float*)d_in[0];
  const float* Wv = (const float*)d_in[1];
  const float* bv = (const float*)d_in[2];
  const float* Wk = (const float*)d_in[3];
  const float* bk = (const float*)d_in[4];
  const float* Wq = (const float*)d_in[5];
  const float* bq = (const float*)d_in[6];
  const float* Wo = (const float*)d_in[7];
  const float* bo = (const float*)d_in[8];
  float* out = (float*)d_out;

  char* ws = (char*)d_ws;
  u16*   P   = (u16*)(ws);                    // [32][8][256][256] bf16: 32 MiB
  u16*   C   = (u16*)(ws + 33554432);         // [32][256][256] bf16:    4 MiB
  float* s_p = (float*)(ws + 37748736);       // [32][8][256] fp32:     32 KiB
  u16*   Ng  = (u16*)(ws + 37781504);         // [32][256][256] bf16:    4 MiB
  float* dv  = (float*)(ws + 41975808);       // [32][256] fp32:        32 KiB

  hipLaunchKernelGGL(k1_xxt,  dim3(8, 32), dim3(1024), 0, stream, x, P, s_p);
  hipLaunchKernelGGL(k2_sum,  dim3(1024),  dim3(256),  0, stream, P, C);
  hipLaunchKernelGGL(k3_chain, dim3(256),  dim3(512),  0, stream,
                     C, Wv, bv, Wk, bk, Wq, bq, Wo, bo, s_p, Ng, dv);
  hipLaunchKernelGGL(k4_out,  dim3(1024),  dim3(512),  0, stream, x, Ng, dv, out);
}